// Round 5
// baseline (88.123 us; speedup 1.0000x reference)
//
#include <hip/hip_runtime.h>
#include <hip/hip_bf16.h>
#include <math.h>

#define N 8192
#define D 128
#define MARGIN_V 0.3f
#define NEG_FILL 1000000.0f

typedef short bf16x8 __attribute__((ext_vector_type(8)));
typedef float f32x4  __attribute__((ext_vector_type(4)));

// Fragment-major layout of Fb: frag (g,q) holds rows 16g..16g+15, k 32q..32q+31,
// stored as 64 lanes x 16B: lane L = row (L&15), k-subchunk (L>>4)*8..+7.
// Short index: ((g*4 + q)*64 + L)*8 + j. One layout serves both A and B operands
// of mfma_f32_16x16x32_bf16 (identical operand mappings).

// ---------- convert: F fp32 -> frag-major bf16, sq, init ap/an ----------
__global__ __launch_bounds__(256) void convert_kernel(const float* __restrict__ F,
                                                      unsigned short* __restrict__ Fb,
                                                      float* __restrict__ sq,
                                                      unsigned* __restrict__ ap,
                                                      unsigned* __restrict__ an) {
    __shared__ float red[16][17];
    const int g   = blockIdx.x;          // row group: 16 rows
    const int tid = threadIdx.x;
    const int q = tid >> 6, L = tid & 63;
    const int m = L & 15, j8 = (L >> 4) * 8;

    const float* src = F + (size_t)(16 * g + m) * D + 32 * q + j8;
    float4 v0 = *(const float4*)src;
    float4 v1 = *(const float4*)(src + 4);

    float s = v0.x * v0.x + v0.y * v0.y + v0.z * v0.z + v0.w * v0.w
            + v1.x * v1.x + v1.y * v1.y + v1.z * v1.z + v1.w * v1.w;

    union { bf16x8 v; __hip_bfloat162 h2[4]; } pk;
    pk.h2[0] = __float22bfloat162_rn({v0.x, v0.y});
    pk.h2[1] = __float22bfloat162_rn({v0.z, v0.w});
    pk.h2[2] = __float22bfloat162_rn({v1.x, v1.y});
    pk.h2[3] = __float22bfloat162_rn({v1.z, v1.w});
    *(bf16x8*)&Fb[(size_t)g * 2048 + tid * 8] = pk.v;   // coalesced 4 KB/block

    red[m][q * 4 + (L >> 4)] = s;
    __syncthreads();
    if (tid < 16) {
        float t = 0.f;
        #pragma unroll
        for (int c = 0; c < 16; ++c) t += red[tid][c];
        sq[16 * g + tid] = t;
    }
    int gid = blockIdx.x * 256 + tid;
    if (gid < N) { ap[gid] = 0u; an[gid] = 0x7F800000u; }   // 0.0f / +inf (d^2 domain)
}

// ---------- gemm: zero-LDS, zero-barrier, frag-major global loads ----------
// Block = strip (128 rows, one 32-row sub-strip per wave) x chunk (512 cols).
// 1024 blocks. Occupancy experiment (R4): per-wave row tile halved 64->32
// (af 64->32 regs, acc 32->16, rowP/N 32->16, labi 16->8; est ~165 VGPR) and
// __launch_bounds__(256,3) caps VGPR at 170 -> 3 waves/SIMD instead of 2.
// Theory: gemm is ~80% latency-stalled at 2 waves/SIMD (round-0 VALU cut was
// neutral); +50% TLP should hide proportionally more stall.
// Waves fully independent: A-frags register-cached and scaled by -2
// in-register, B-frags double-buffered global->register. MFMA accumulator
// initialized to sqj so the chain yields u = sqj - 2<ai,aj> directly.
__global__ __launch_bounds__(256, 3) void gemm_kernel(const unsigned short* __restrict__ Fb,
                                                      const float* __restrict__ sq,
                                                      const int* __restrict__ lab,
                                                      unsigned* __restrict__ ap,
                                                      unsigned* __restrict__ an) {
    const int tid  = threadIdx.x;
    const int wave = tid >> 6, lane = tid & 63;
    const int quad = lane >> 4, lr = lane & 15;
    const int S = blockIdx.x >> 4;        // strip: 128 rows (64 strips)
    const int C = blockIdx.x & 15;        // chunk: 512 cols (16 chunks)
    const int R0   = S * 128 + wave * 32; // this wave's 32 rows
    const int g0   = R0 >> 4;             // row-group base (2 groups)
    const int cg0  = C * 32;              // col-group base (32 groups)
    const int colb = C * 512;

    // A fragments: 2 row-groups x 4 k-chunks, coalesced contiguous loads,
    // then scaled by -2 in-register (exact for bf16 normals; +-0 maps to
    // -+2^-126, numerically negligible).
    bf16x8 af[2][4];
    #pragma unroll
    for (int a = 0; a < 2; ++a)
        #pragma unroll
        for (int ks = 0; ks < 4; ++ks) {
            af[a][ks] = *(const bf16x8*)&Fb[(((size_t)(g0 + a) * 4 + ks) * 64 + lane) * 8];
            unsigned* uw = (unsigned*)&af[a][ks];
            #pragma unroll
            for (int w = 0; w < 4; ++w)
                uw[w] = (uw[w] + 0x00800080u) ^ 0x80008000u;   // packed bf16 *(-2)
        }

    int4 labi4[2];
    #pragma unroll
    for (int a = 0; a < 2; ++a)
        labi4[a] = *(const int4*)&lab[R0 + a * 16 + quad * 4];

    float rowP[2][4], rowN[2][4];
    #pragma unroll
    for (int a = 0; a < 2; ++a)
        #pragma unroll
        for (int r = 0; r < 4; ++r) { rowP[a][r] = -INFINITY; rowN[a][r] = INFINITY; }

#define LOADT(T, BF, SQJ, LABJ)                                                   \
    {                                                                             \
        _Pragma("unroll")                                                         \
        for (int b = 0; b < 2; ++b) {                                             \
            int gb = cg0 + 2 * (T) + b;                                           \
            _Pragma("unroll")                                                     \
            for (int ks = 0; ks < 4; ++ks)                                        \
                BF[b][ks] = *(const bf16x8*)&Fb[(((size_t)gb * 4 + ks) * 64 + lane) * 8]; \
            SQJ[b]  = sq[colb + (T) * 32 + b * 16 + lr];                          \
            LABJ[b] = lab[colb + (T) * 32 + b * 16 + lr];                         \
        }                                                                         \
    }

#define COMP(BF, SQJ, LABJ)                                                       \
    {                                                                             \
        f32x4 acc[2][2];                                                          \
        _Pragma("unroll")                                                         \
        for (int a = 0; a < 2; ++a)                                               \
            _Pragma("unroll")                                                     \
            for (int b = 0; b < 2; ++b)                                           \
                acc[a][b] = {SQJ[b], SQJ[b], SQJ[b], SQJ[b]};                     \
        _Pragma("unroll")                                                         \
        for (int ks = 0; ks < 4; ++ks)                                            \
            _Pragma("unroll")                                                     \
            for (int a = 0; a < 2; ++a)                                           \
                _Pragma("unroll")                                                 \
                for (int b = 0; b < 2; ++b)                                       \
                    acc[a][b] = __builtin_amdgcn_mfma_f32_16x16x32_bf16(          \
                        af[a][ks], BF[b][ks], acc[a][b], 0, 0, 0);                \
        _Pragma("unroll")                                                         \
        for (int a = 0; a < 2; ++a)                                               \
            _Pragma("unroll")                                                     \
            for (int r = 0; r < 4; ++r) {                                         \
                float u0 = acc[a][0][r], u1 = acc[a][1][r];                       \
                bool s0 = (labi4[a][r] == LABJ[0]);                               \
                bool s1 = (labi4[a][r] == LABJ[1]);                               \
                float p0 = s0 ? u0 : -INFINITY;                                   \
                float p1 = s1 ? u1 : -INFINITY;                                   \
                float n0 = s0 ? INFINITY : u0;                                    \
                float n1 = s1 ? INFINITY : u1;                                    \
                rowP[a][r] = fmaxf(fmaxf(rowP[a][r], p0), p1);                    \
                rowN[a][r] = fminf(fminf(rowN[a][r], n0), n1);                    \
            }                                                                     \
    }

    bf16x8 b0[2][4], b1[2][4];
    float sq0[2], sq1[2];
    int   lb0[2], lb1[2];
    LOADT(0, b0, sq0, lb0);
    #pragma unroll 1
    for (int t = 0; t < 16; t += 2) {
        LOADT(t + 1, b1, sq1, lb1);
        COMP(b0, sq0, lb0);
        if (t + 2 < 16) LOADT(t + 2, b0, sq0, lb0);
        COMP(b1, sq1, lb1);
    }
#undef LOADT
#undef COMP

    // reduce over the 16 lr lanes, add sqi (loaded only now: not live in the
    // hot loop), clamp, atomic d^2-bit combine
    #pragma unroll
    for (int a = 0; a < 2; ++a)
        #pragma unroll
        for (int r = 0; r < 4; ++r) {
            float p = rowP[a][r], n = rowN[a][r];
            #pragma unroll
            for (int off = 1; off < 16; off <<= 1) {
                p = fmaxf(p, __shfl_xor(p, off));
                n = fminf(n, __shfl_xor(n, off));
            }
            rowP[a][r] = p; rowN[a][r] = n;
        }
    if (lr == 0) {
        #pragma unroll
        for (int a = 0; a < 2; ++a) {
            f32x4 sqi4 = *(const f32x4*)&sq[R0 + a * 16 + quad * 4];
            #pragma unroll
            for (int r = 0; r < 4; ++r) {
                int row = R0 + a * 16 + quad * 4 + r;
                float pd2 = fmaxf(sqi4[r] + rowP[a][r], 0.f);   // -inf -> 0 (no-op vs init)
                float nd2 = fmaxf(sqi4[r] + rowN[a][r], 0.f);   // +inf stays +inf (no-op)
                atomicMax(&ap[row], __float_as_uint(pd2));
                atomicMin(&an[row], __float_as_uint(nd2));
            }
        }
    }
}

// ---------- loss: single block, reads d^2, sqrt here, writes out[0] ----------
__global__ __launch_bounds__(256) void loss_kernel(const float* __restrict__ ap,
                                                   const float* __restrict__ an,
                                                   float* __restrict__ out) {
    int tid = threadIdx.x;
    float sum = 0.f;
    #pragma unroll
    for (int k = 0; k < 8; ++k) {
        int i = k * 1024 + tid * 4;
        f32x4 a4 = *(const f32x4*)&ap[i];
        f32x4 n4 = *(const f32x4*)&an[i];
        #pragma unroll
        for (int c = 0; c < 4; ++c) {
            float apd = __builtin_amdgcn_sqrtf(a4[c]);
            float anv = n4[c];
            float and_ = (anv < INFINITY) ? __builtin_amdgcn_sqrtf(anv) : NEG_FILL;
            sum += fmaxf(0.f, MARGIN_V - (and_ - apd));
        }
    }
    #pragma unroll
    for (int off = 32; off >= 1; off >>= 1) sum += __shfl_xor(sum, off);
    __shared__ float s4[4];
    if ((tid & 63) == 0) s4[tid >> 6] = sum;
    __syncthreads();
    if (tid == 0) out[0] = (s4[0] + s4[1] + s4[2] + s4[3]) * (1.0f / (float)N);
}

extern "C" void kernel_launch(void* const* d_in, const int* in_sizes, int n_in,
                              void* d_out, int out_size, void* d_ws, size_t ws_size,
                              hipStream_t stream) {
    const float* F   = (const float*)d_in[0];
    const int*   lab = (const int*)d_in[1];

    unsigned short* Fb = (unsigned short*)d_ws;          // 2 MB, frag-major
    float*          sq = (float*)(Fb + (size_t)N * D);   // 32 KB
    unsigned*       ap = (unsigned*)(sq + N);            // 32 KB
    unsigned*       an = ap + N;                         // 32 KB

    convert_kernel<<<N / 16, 256, 0, stream>>>(F, Fb, sq, ap, an);
    gemm_kernel<<<1024, 256, 0, stream>>>(Fb, sq, lab, ap, an);
    loss_kernel<<<1, 256, 0, stream>>>((const float*)ap, (const float*)an, (float*)d_out);
}

// Round 10
// 84.886 us; speedup vs baseline: 1.0381x; 1.0381x over previous
//
#include <hip/hip_runtime.h>
#include <hip/hip_bf16.h>
#include <math.h>

#define N 8192
#define D 128
#define MARGIN_V 0.3f
#define NEG_FILL 1000000.0f

typedef short bf16x8 __attribute__((ext_vector_type(8)));
typedef float f32x4  __attribute__((ext_vector_type(4)));

typedef __attribute__((address_space(1))) const unsigned short g_us;
typedef __attribute__((address_space(3))) unsigned short l_us;

// Fragment-major layout of Fb: frag (g,q) holds rows 16g..16g+15, k 32q..32q+31,
// stored as 64 lanes x 16B: lane L = row (L&15), k-subchunk (L>>4)*8..+7.
// Short index: ((g*4 + q)*64 + L)*8 + j.

// ---------- convert: F fp32 -> frag-major bf16, sq, init ap/an ----------
__global__ __launch_bounds__(256) void convert_kernel(const float* __restrict__ F,
                                                      unsigned short* __restrict__ Fb,
                                                      float* __restrict__ sq,
                                                      unsigned* __restrict__ ap,
                                                      unsigned* __restrict__ an) {
    __shared__ float red[16][17];
    const int g   = blockIdx.x;          // row group: 16 rows
    const int tid = threadIdx.x;
    const int q = tid >> 6, L = tid & 63;
    const int m = L & 15, j8 = (L >> 4) * 8;

    const float* src = F + (size_t)(16 * g + m) * D + 32 * q + j8;
    float4 v0 = *(const float4*)src;
    float4 v1 = *(const float4*)(src + 4);

    float s = v0.x * v0.x + v0.y * v0.y + v0.z * v0.z + v0.w * v0.w
            + v1.x * v1.x + v1.y * v1.y + v1.z * v1.z + v1.w * v1.w;

    union { bf16x8 v; __hip_bfloat162 h2[4]; } pk;
    pk.h2[0] = __float22bfloat162_rn({v0.x, v0.y});
    pk.h2[1] = __float22bfloat162_rn({v0.z, v0.w});
    pk.h2[2] = __float22bfloat162_rn({v1.x, v1.y});
    pk.h2[3] = __float22bfloat162_rn({v1.z, v1.w});
    *(bf16x8*)&Fb[(size_t)g * 2048 + tid * 8] = pk.v;   // coalesced 4 KB/block

    red[m][q * 4 + (L >> 4)] = s;
    __syncthreads();
    if (tid < 16) {
        float t = 0.f;
        #pragma unroll
        for (int c = 0; c < 16; ++c) t += red[tid][c];
        sq[16 * g + tid] = t;
    }
    int gid = blockIdx.x * 256 + tid;
    if (gid < N) { ap[gid] = 0u; an[gid] = 0x7F800000u; }   // 0.0f / +inf (d^2 domain)
}

// ---------- gemm: LDS-staged B (R8 structural change) ----------
// Block = strip (256 rows, one 64-row sub-strip per wave) x chunk (512 cols),
// 512 blocks = 2/CU. B fragments staged once per block into LDS via
// global_load_lds (16B, fire-and-forget, no VGPR round-trip), double-buffered
// 2 x 8KB, consumed via conflict-free ds_read_b128 (lane*16B contiguous).
// Replaces 4 waves privately streaming the same 128KB B-chunk through L1
// (160 VMEM insts/wave -> ~40). Sync: bar1 (WAR guard) -> STAGE(t+1) ->
// bar2 (implicit vmcnt(0) drain = RAW guard) -> COMP(t); m97 pattern, drain
// hidden by the co-resident second block. Math bitwise-identical to R4.
__global__ __launch_bounds__(256, 2) void gemm_kernel(const unsigned short* __restrict__ Fb,
                                                      const float* __restrict__ sq,
                                                      const int* __restrict__ lab,
                                                      unsigned* __restrict__ ap,
                                                      unsigned* __restrict__ an) {
    __shared__ unsigned short Bs[2][4096];   // 2 x 8KB B double-buffer
    const int tid  = threadIdx.x;
    const int wave = tid >> 6, lane = tid & 63;
    const int quad = lane >> 4, lr = lane & 15;
    const int S = blockIdx.x >> 4;        // strip: 256 rows
    const int C = blockIdx.x & 15;        // chunk: 512 cols
    const int R0   = S * 256 + wave * 64; // this wave's 64 rows
    const int g0   = R0 >> 4;             // row-group base (4 groups)
    const int cg0  = C * 32;              // col-group base (32 groups)
    const int colb = C * 512;

    // A fragments: register-cached, scaled by -2 in-register (bf16 exact for
    // normals; +-0 -> -+2^-126, negligible). MFMA acc inits to sqj, so the
    // chain yields u = sqj - 2<ai,aj> directly.
    bf16x8 af[4][4];
    #pragma unroll
    for (int a = 0; a < 4; ++a)
        #pragma unroll
        for (int ks = 0; ks < 4; ++ks) {
            af[a][ks] = *(const bf16x8*)&Fb[(((size_t)(g0 + a) * 4 + ks) * 64 + lane) * 8];
            unsigned* uw = (unsigned*)&af[a][ks];
            #pragma unroll
            for (int w = 0; w < 4; ++w)
                uw[w] = (uw[w] + 0x00800080u) ^ 0x80008000u;   // packed bf16 *(-2)
        }

    int4 labi4[4];
    #pragma unroll
    for (int a = 0; a < 4; ++a)
        labi4[a] = *(const int4*)&lab[R0 + a * 16 + quad * 4];

    float rowP[4][4], rowN[4][4];
    #pragma unroll
    for (int a = 0; a < 4; ++a)
        #pragma unroll
        for (int r = 0; r < 4; ++r) { rowP[a][r] = -INFINITY; rowN[a][r] = INFINITY; }

// Stage T-step T (2 col-groups = 8KB) into buffer P. Per thread: two 16B
// global_load_lds. LDS dest = wave-uniform base + lane*16 (HW rule); source
// is per-lane, both sides linear in the identical frag-major order.
#define STAGE(T, P)                                                               \
    {                                                                             \
        const unsigned short* gs = Fb + (size_t)(cg0 + 2 * (T)) * 2048;           \
        _Pragma("unroll")                                                         \
        for (int i = 0; i < 2; ++i)                                               \
            __builtin_amdgcn_global_load_lds(                                     \
                (g_us*)(gs + i * 2048 + wave * 512 + lane * 8),                   \
                (l_us*)&Bs[P][i * 2048 + wave * 512], 16, 0, 0);                  \
    }

#define LOADSL(T, SQ, LB)                                                         \
    {                                                                             \
        _Pragma("unroll")                                                         \
        for (int b = 0; b < 2; ++b) {                                             \
            SQ[b] = sq[colb + (T) * 32 + b * 16 + lr];                            \
            LB[b] = lab[colb + (T) * 32 + b * 16 + lr];                           \
        }                                                                         \
    }

#define COMP(P, SQJ, LABJ)                                                        \
    {                                                                             \
        bf16x8 bfr[2][4];                                                         \
        _Pragma("unroll")                                                         \
        for (int b = 0; b < 2; ++b)                                               \
            _Pragma("unroll")                                                     \
            for (int ks = 0; ks < 4; ++ks)                                        \
                bfr[b][ks] = *(const bf16x8*)&Bs[P][b * 2048 + ks * 512 + lane * 8]; \
        f32x4 acc[4][2];                                                          \
        _Pragma("unroll")                                                         \
        for (int a = 0; a < 4; ++a)                                               \
            _Pragma("unroll")                                                     \
            for (int b = 0; b < 2; ++b)                                           \
                acc[a][b] = {SQJ[b], SQJ[b], SQJ[b], SQJ[b]};                     \
        _Pragma("unroll")                                                         \
        for (int ks = 0; ks < 4; ++ks)                                            \
            _Pragma("unroll")                                                     \
            for (int a = 0; a < 4; ++a)                                           \
                _Pragma("unroll")                                                 \
                for (int b = 0; b < 2; ++b)                                       \
                    acc[a][b] = __builtin_amdgcn_mfma_f32_16x16x32_bf16(          \
                        af[a][ks], bfr[b][ks], acc[a][b], 0, 0, 0);               \
        _Pragma("unroll")                                                         \
        for (int a = 0; a < 4; ++a)                                               \
            _Pragma("unroll")                                                     \
            for (int r = 0; r < 4; ++r) {                                         \
                float u0 = acc[a][0][r], u1 = acc[a][1][r];                       \
                bool s0 = (labi4[a][r] == LABJ[0]);                               \
                bool s1 = (labi4[a][r] == LABJ[1]);                               \
                float p0 = s0 ? u0 : -INFINITY;                                   \
                float p1 = s1 ? u1 : -INFINITY;                                   \
                float n0 = s0 ? INFINITY : u0;                                    \
                float n1 = s1 ? INFINITY : u1;                                    \
                rowP[a][r] = fmaxf(fmaxf(rowP[a][r], p0), p1);                    \
                rowN[a][r] = fminf(fminf(rowN[a][r], n0), n1);                    \
            }                                                                     \
    }

    float sqc[2], sqn[2];
    int   lbc[2], lbn[2];
    STAGE(0, 0);
    LOADSL(0, sqc, lbc);
    #pragma unroll 1
    for (int t = 0; t < 16; ++t) {
        __syncthreads();                       // WAR: all compute(t-1) reads done
        if (t + 1 < 16) {
            STAGE(t + 1, (t + 1) & 1);
            LOADSL(t + 1, sqn, lbn);
        }
        __syncthreads();                       // RAW: implicit vmcnt(0) drain -> buf[t&1], sqc ready
        COMP(t & 1, sqc, lbc);
        if (t + 1 < 16) {
            sqc[0] = sqn[0]; sqc[1] = sqn[1];
            lbc[0] = lbn[0]; lbc[1] = lbn[1];
        }
    }
#undef STAGE
#undef LOADSL
#undef COMP

    // reduce over the 16 lr lanes, add sqi, clamp, atomic d^2-bit combine
    #pragma unroll
    for (int a = 0; a < 4; ++a)
        #pragma unroll
        for (int r = 0; r < 4; ++r) {
            float p = rowP[a][r], n = rowN[a][r];
            #pragma unroll
            for (int off = 1; off < 16; off <<= 1) {
                p = fmaxf(p, __shfl_xor(p, off));
                n = fminf(n, __shfl_xor(n, off));
            }
            rowP[a][r] = p; rowN[a][r] = n;
        }
    if (lr == 0) {
        #pragma unroll
        for (int a = 0; a < 4; ++a) {
            f32x4 sqi4 = *(const f32x4*)&sq[R0 + a * 16 + quad * 4];
            #pragma unroll
            for (int r = 0; r < 4; ++r) {
                int row = R0 + a * 16 + quad * 4 + r;
                float pd2 = fmaxf(sqi4[r] + rowP[a][r], 0.f);   // -inf -> 0 (no-op vs init)
                float nd2 = fmaxf(sqi4[r] + rowN[a][r], 0.f);   // +inf stays +inf (no-op)
                atomicMax(&ap[row], __float_as_uint(pd2));
                atomicMin(&an[row], __float_as_uint(nd2));
            }
        }
    }
}

// ---------- loss: single block, reads d^2, sqrt here, writes out[0] ----------
__global__ __launch_bounds__(256) void loss_kernel(const float* __restrict__ ap,
                                                   const float* __restrict__ an,
                                                   float* __restrict__ out) {
    int tid = threadIdx.x;
    float sum = 0.f;
    #pragma unroll
    for (int k = 0; k < 8; ++k) {
        int i = k * 1024 + tid * 4;
        f32x4 a4 = *(const f32x4*)&ap[i];
        f32x4 n4 = *(const f32x4*)&an[i];
        #pragma unroll
        for (int c = 0; c < 4; ++c) {
            float apd = __builtin_amdgcn_sqrtf(a4[c]);
            float anv = n4[c];
            float and_ = (anv < INFINITY) ? __builtin_amdgcn_sqrtf(anv) : NEG_FILL;
            sum += fmaxf(0.f, MARGIN_V - (and_ - apd));
        }
    }
    #pragma unroll
    for (int off = 32; off >= 1; off >>= 1) sum += __shfl_xor(sum, off);
    __shared__ float s4[4];
    if ((tid & 63) == 0) s4[tid >> 6] = sum;
    __syncthreads();
    if (tid == 0) out[0] = (s4[0] + s4[1] + s4[2] + s4[3]) * (1.0f / (float)N);
}

extern "C" void kernel_launch(void* const* d_in, const int* in_sizes, int n_in,
                              void* d_out, int out_size, void* d_ws, size_t ws_size,
                              hipStream_t stream) {
    const float* F   = (const float*)d_in[0];
    const int*   lab = (const int*)d_in[1];

    unsigned short* Fb = (unsigned short*)d_ws;          // 2 MB, frag-major
    float*          sq = (float*)(Fb + (size_t)N * D);   // 32 KB
    unsigned*       ap = (unsigned*)(sq + N);            // 32 KB
    unsigned*       an = ap + N;                         // 32 KB

    convert_kernel<<<N / 16, 256, 0, stream>>>(F, Fb, sq, ap, an);
    gemm_kernel<<<512, 256, 0, stream>>>(Fb, sq, lab, ap, an);
    loss_kernel<<<1, 256, 0, stream>>>((const float*)ap, (const float*)an, (float*)d_out);
}